// Round 12
// baseline (188.391 us; speedup 1.0000x reference)
//
#include <hip/hip_runtime.h>
#include <hip/hip_bf16.h>

#define DI __device__ __forceinline__

typedef __attribute__((ext_vector_type(8))) short short8;
typedef __attribute__((ext_vector_type(4))) short short4v;
typedef __attribute__((ext_vector_type(4))) float f32x4;

// Q pre-scale: 1/sqrt(64) * log2(e)  (exp2-domain softmax)
#define QSCALE 0.180336885f

// RNE float -> bf16 via native fptrunc (compiler packs v_cvt_pk_bf16_f32)
DI short f2bf(float f) {
  __hip_bfloat16 h = __float2bfloat16(f);
  return __builtin_bit_cast(short, h);
}

DI float fexp2(float x) {
#if __has_builtin(__builtin_amdgcn_exp2f)
  return __builtin_amdgcn_exp2f(x);
#else
  return exp2f(x);
#endif
}

// async global->LDS, 16B per lane. LDS dest = wave-uniform base + lane*16.
DI void gl16(const short* g, short* l) {
  __builtin_amdgcn_global_load_lds(
      (const __attribute__((address_space(1))) void*)g,
      (__attribute__((address_space(3))) void*)l, 16, 0, 0);
}

// ---------------------------------------------------------------------------
// Weight conversion only (q/k/v conversion is fused into proj_gemm3).
// z = 0..3 selects Wq/Wk/Wv/Wo; 512 blocks x 256 thr x 8 elems = 1M elems.
// ---------------------------------------------------------------------------
__global__ __launch_bounds__(256) void convert_w4(
    const float* __restrict__ wq, const float* __restrict__ wk,
    const float* __restrict__ wv, const float* __restrict__ wo,
    short* __restrict__ wb) {
  int z = blockIdx.z;
  const float* src = (z == 0) ? wq : (z == 1) ? wk : (z == 2) ? wv : wo;
  short* dst = wb + (size_t)z * 1024 * 1024;
  size_t i = ((size_t)blockIdx.x * 256 + threadIdx.x) * 8;
  float4 f0 = *(const float4*)(src + i);
  float4 f1 = *(const float4*)(src + i + 4);
  short8 o;
  o[0] = f2bf(f0.x); o[1] = f2bf(f0.y); o[2] = f2bf(f0.z); o[3] = f2bf(f0.w);
  o[4] = f2bf(f1.x); o[5] = f2bf(f1.y); o[6] = f2bf(f1.z); o[7] = f2bf(f1.w);
  *(short8*)(dst + i) = o;
}

// ---------------------------------------------------------------------------
// GEMM core, dbuf (1 barrier/K-step). A either fp32 (reg-staged: fused
// convert; loads for t+1 issue before compute -> latency hidden; cvt +
// swizzled ds_write land after compute, before the barrier) or bf16 (gl16).
// B always gl16 (inverse-swizzled source, linear LDS dest, XOR'd ds_read).
// OMODE: 0 = fp32 row-major; 1 = bf16 [B,H,S,Dh]; 2 = bf16 [B,H,Dh,S].
// ---------------------------------------------------------------------------
enum { OUT_F32 = 0, OUT_HEAD = 1, OUT_HEADT = 2 };

DI void stage_B(const short* __restrict__ B, short* dB, int bn, int k0,
                int wid, int lrr, int lch) {
#pragma unroll
  for (int i = 0; i < 4; ++i) {
    int r0 = wid * 32 + i * 8;
    int rr = r0 + lrr;
    int sc = (lch ^ (rr & 7)) << 3;
    gl16(B + (size_t)(bn + rr) * 1024 + k0 + sc, dB + r0 * 64);
  }
}

DI void stage_A16(const short* __restrict__ A, short* dA, int bm, int k0,
                  int wid, int lrr, int lch) {
#pragma unroll
  for (int i = 0; i < 4; ++i) {
    int r0 = wid * 32 + i * 8;
    int rr = r0 + lrr;
    int sc = (lch ^ (rr & 7)) << 3;
    gl16(A + (size_t)(bm + rr) * 1024 + k0 + sc, dA + r0 * 64);
  }
}

template <int OMODE, bool AF32>
DI void gemm_core(short* sA, short* sB, const void* __restrict__ Ap,
                  const short* __restrict__ B, void* __restrict__ Cp,
                  float scale, int bm, int bn) {
  const int tid = threadIdx.x;
  const int lane = tid & 63;
  const int wid = tid >> 6;
  const int wm = wid >> 1, wn = wid & 1;
  const int l15 = lane & 15, lq = lane >> 4;
  const int lrr = lane >> 3;  // row within 8-row group
  const int lch = lane & 7;   // 16B chunk within 128B row

  const float* Af = (const float*)Ap;
  const short* Ab = (const short*)Ap;

  f32x4 acc[4][4] = {};
  float4 fa[4][2];  // staged fp32 A regs (AF32 path), static-indexed

  // ---- prologue: tile 0 ----
  if (AF32) {
#pragma unroll
    for (int t = 0; t < 4; ++t) {
      int c = tid + t * 256;
      int row = c >> 3, col = (c & 7) * 8;
      const float* src = Af + (size_t)(bm + row) * 1024 + col;
      fa[t][0] = *(const float4*)src;
      fa[t][1] = *(const float4*)(src + 4);
    }
    stage_B(B, sB, bn, 0, wid, lrr, lch);
#pragma unroll
    for (int t = 0; t < 4; ++t) {
      int c = tid + t * 256;
      int row = c >> 3, col = (c & 7) * 8;
      short8 vv;
      vv[0] = f2bf(fa[t][0].x); vv[1] = f2bf(fa[t][0].y);
      vv[2] = f2bf(fa[t][0].z); vv[3] = f2bf(fa[t][0].w);
      vv[4] = f2bf(fa[t][1].x); vv[5] = f2bf(fa[t][1].y);
      vv[6] = f2bf(fa[t][1].z); vv[7] = f2bf(fa[t][1].w);
      int off = (row * 128 + col * 2) ^ ((row & 7) << 4);
      *(short8*)((char*)sA + off) = vv;
    }
  } else {
    stage_A16(Ab, sA, bm, 0, wid, lrr, lch);
    stage_B(B, sB, bn, 0, wid, lrr, lch);
  }
  __syncthreads();

  int cur = 0;
  for (int t16 = 0; t16 < 16; ++t16) {
    const bool more = (t16 + 1 < 16);
    // ---- issue next tile's loads (hidden under compute) ----
    if (more) {
      int k1 = (t16 + 1) * 64;
      if (AF32) {
#pragma unroll
        for (int t = 0; t < 4; ++t) {
          int c = tid + t * 256;
          int row = c >> 3, col = (c & 7) * 8;
          const float* src = Af + (size_t)(bm + row) * 1024 + k1 + col;
          fa[t][0] = *(const float4*)src;
          fa[t][1] = *(const float4*)(src + 4);
        }
      } else {
        stage_A16(Ab, sA + (cur ^ 1) * 8192, bm, k1, wid, lrr, lch);
      }
      stage_B(B, sB + (cur ^ 1) * 8192, bn, k1, wid, lrr, lch);
    }

    // ---- compute current tile ----
    const char* bA = (const char*)(sA + cur * 8192);
    const char* bB = (const char*)(sB + cur * 8192);
#pragma unroll
    for (int ks = 0; ks < 2; ++ks) {
      short8 a[4], b[4];
#pragma unroll
      for (int mt = 0; mt < 4; ++mt) {
        int row = wm * 64 + mt * 16 + l15;
        int off = (row * 128 + ks * 64 + lq * 16) ^ ((row & 7) << 4);
        a[mt] = *(const short8*)(bA + off);
      }
#pragma unroll
      for (int nt = 0; nt < 4; ++nt) {
        int row = wn * 64 + nt * 16 + l15;
        int off = (row * 128 + ks * 64 + lq * 16) ^ ((row & 7) << 4);
        b[nt] = *(const short8*)(bB + off);
      }
#pragma unroll
      for (int mt = 0; mt < 4; ++mt)
#pragma unroll
        for (int nt = 0; nt < 4; ++nt) {
          if (OMODE == OUT_HEADT)
            acc[mt][nt] = __builtin_amdgcn_mfma_f32_16x16x32_bf16(
                b[nt], a[mt], acc[mt][nt], 0, 0, 0);
          else
            acc[mt][nt] = __builtin_amdgcn_mfma_f32_16x16x32_bf16(
                a[mt], b[nt], acc[mt][nt], 0, 0, 0);
        }
    }

    // ---- write staged A regs -> bufA^1 (AF32 path) ----
    if (AF32 && more) {
      short* dA = sA + (cur ^ 1) * 8192;
#pragma unroll
      for (int t = 0; t < 4; ++t) {
        int c = tid + t * 256;
        int row = c >> 3, col = (c & 7) * 8;
        short8 vv;
        vv[0] = f2bf(fa[t][0].x); vv[1] = f2bf(fa[t][0].y);
        vv[2] = f2bf(fa[t][0].z); vv[3] = f2bf(fa[t][0].w);
        vv[4] = f2bf(fa[t][1].x); vv[5] = f2bf(fa[t][1].y);
        vv[6] = f2bf(fa[t][1].z); vv[7] = f2bf(fa[t][1].w);
        int off = (row * 128 + col * 2) ^ ((row & 7) << 4);
        *(short8*)((char*)dA + off) = vv;
      }
    }
    __syncthreads();
    cur ^= 1;
  }

  // ---- epilogue ----
#pragma unroll
  for (int mt = 0; mt < 4; ++mt) {
#pragma unroll
    for (int nt = 0; nt < 4; ++nt) {
#pragma unroll
      for (int r = 0; r < 4; ++r) {
        float val = acc[mt][nt][r] * scale;
        if (OMODE == OUT_HEADT) {
          int f = bn + wn * 64 + nt * 16 + lq * 4 + r;
          int t = bm + wm * 64 + mt * 16 + l15;
          int bb = t >> 11, s = t & 2047;
          int h = f >> 6, dh = f & 63;
          ((short*)Cp)[((size_t)((bb * 16 + h) * 64 + dh)) * 2048 + s] = f2bf(val);
        } else {
          int rowg = bm + wm * 64 + mt * 16 + lq * 4 + r;
          int colg = bn + wn * 64 + nt * 16 + l15;
          if (OMODE == OUT_HEAD) {
            int bb = rowg >> 11, s = rowg & 2047;
            int h = colg >> 6, dh = colg & 63;
            ((short*)Cp)[((size_t)(bb * 16 + h) * 2048 + s) * 64 + dh] = f2bf(val);
          } else {
            ((float*)Cp)[(size_t)rowg * 1024 + colg] = val;
          }
        }
      }
    }
  }
}

// XCD-aware tile mapping: 8 n-tiles of one A row-panel run consecutively on
// ONE XCD (id&7 = xcd under round-robin dispatch) -> A panel read once.
DI void xcd_map(int id, int& bm, int& bn) {
  int xcd = id & 7, slot = id >> 3;
  int panel = xcd + 8 * (slot >> 3);
  int ntile = slot & 7;
  bm = panel * 128;
  bn = ntile * 128;
}

#define GEMM_LDS()                                  \
  __shared__ __align__(16) short sA[2 * 128 * 64];  \
  __shared__ __align__(16) short sB[2 * 128 * 64];

// fused fp32->bf16 projection GEMM: A = q/k/v fp32 inputs directly
__global__ __launch_bounds__(256) void proj_gemm3(
    const float* __restrict__ q, const float* __restrict__ k,
    const float* __restrict__ v, const short* __restrict__ wq,
    const short* __restrict__ wk, const short* __restrict__ wv,
    short* __restrict__ xq, short* __restrict__ xk, short* __restrict__ xvT) {
  GEMM_LDS();
  int z = blockIdx.z;
  int bm, bn;
  xcd_map(blockIdx.x, bm, bn);
  if (z == 0) {
    gemm_core<OUT_HEAD, true>(sA, sB, q, wq, xq, QSCALE, bm, bn);
  } else if (z == 1) {
    gemm_core<OUT_HEAD, true>(sA, sB, k, wk, xk, 1.0f, bm, bn);
  } else {
    gemm_core<OUT_HEADT, true>(sA, sB, v, wv, xvT, 1.0f, bm, bn);
  }
}

__global__ __launch_bounds__(256) void final_gemm(
    const short* __restrict__ oa, const short* __restrict__ wo,
    float* __restrict__ out) {
  GEMM_LDS();
  int bm, bn;
  xcd_map(blockIdx.x, bm, bn);
  gemm_core<OUT_F32, false>(sA, sB, oa, wo, out, 1.0f, bm, bn);
}

// ---------------------------------------------------------------------------
// Causal flash attention (known-good R8/R9 version, unchanged).
// 512 threads = 8 waves; 128-row q-supertile; pairs (i, 15-i) -> 34 KV
// tiles/block, 512 blocks. Double-buffered K/V^T LDS, ONE barrier per tile.
// LDS = 32KB (K,VT dbuf) + 16KB (P) = 48KB.
// ---------------------------------------------------------------------------
__global__ __launch_bounds__(512, 4) void attn_k(
    const short* __restrict__ Xq, const short* __restrict__ Xk,
    const short* __restrict__ XvT, short* __restrict__ Oa) {
  __shared__ __align__(16) short sK[2][64 * 64];
  __shared__ __align__(16) short sVT[2][64 * 64];
  __shared__ __align__(16) short sP[8][16 * 64];

  const int tid = threadIdx.x;
  const int lane = tid & 63;
  const int wid = tid >> 6;  // 0..7
  const int l15 = lane & 15, lq = lane >> 4;
  const int bid = blockIdx.x;
  const int ipair = bid >> 6;  // 0..7
  const int bh = bid & 63;     // same-bh blocks land on same XCD
  const int b = bh >> 4, h = bh & 15;

  const short* Q = Xq + (size_t)bh * 2048 * 64;
  const short* K = Xk + (size_t)bh * 2048 * 64;
  const short* VT = XvT + (size_t)bh * 64 * 2048;

  const int srow = tid >> 3;       // 0..63
  const int scol = (tid & 7) * 8;  // 0..56
  const int soff = (srow * 128 + scol * 2) ^ ((srow & 7) << 4);

  short8 kreg, vreg;
  kreg = *(const short8*)(K + (size_t)srow * 64 + scol);
  vreg = *(const short8*)(VT + (size_t)srow * 2048 + scol);

  *(short8*)((char*)sK[0] + soff) = kreg;
  *(short8*)((char*)sVT[0] + soff) = vreg;

  short* sPw = sP[wid];
  int p = 0;

  for (int seg = 0; seg < 2; ++seg) {
    const int qt = seg ? ipair : (15 - ipair);  // long supertile first
    const int qfirst = qt * 128 + wid * 16;
    const int qg = qfirst + l15;
    const int qlast = qfirst + 15;
    const int ntile = 2 * qt + 2;

    short8 qf[2];
#pragma unroll
    for (int ks = 0; ks < 2; ++ks)
      qf[ks] = *(const short8*)(Q + (size_t)qg * 64 + ks * 32 + lq * 8);

    float m_run = -1e30f, l_run = 0.f;
    f32x4 acc[4] = {};

    for (int kt = 0; kt < ntile; ++kt) {
      const int kv0 = kt * 64;
      __syncthreads();

      int nkt = kt + 1, nseg = seg;
      if (nkt >= ntile) { nseg = seg + 1; nkt = 0; }
      const bool hn = (nseg < 2);
      if (hn) {
        const int kn = nkt * 64;
        kreg = *(const short8*)(K + (size_t)(kn + srow) * 64 + scol);
        vreg = *(const short8*)(VT + (size_t)srow * 2048 + kn + scol);
      }

      const bool fullmask = (kv0 > qlast);
      if (!fullmask) {
        const bool needmask = (kv0 + 63 > qfirst);
        const char* bufK = (const char*)sK[p];
        const char* bufV = (const char*)sVT[p];

        f32x4 sc[4] = {};
        __builtin_amdgcn_s_setprio(1);
#pragma unroll
        for (int ks = 0; ks < 2; ++ks) {
          short8 kf[4];
#pragma unroll
          for (int nt = 0; nt < 4; ++nt) {
            int row = nt * 16 + l15;
            int off = (row * 128 + ks * 64 + lq * 16) ^ ((row & 7) << 4);
            kf[nt] = *(const short8*)(bufK + off);
          }
#pragma unroll
          for (int nt = 0; nt < 4; ++nt)
            sc[nt] = __builtin_amdgcn_mfma_f32_16x16x32_bf16(kf[nt], qf[ks],
                                                             sc[nt], 0, 0, 0);
        }
        __builtin_amdgcn_s_setprio(0);

        float pv[4][4];
        float m = -1e30f;
        if (needmask) {
#pragma unroll
          for (int nt = 0; nt < 4; ++nt)
#pragma unroll
            for (int r = 0; r < 4; ++r) {
              float s = sc[nt][r];
              if (kv0 + nt * 16 + lq * 4 + r > qg) s = -1e30f;
              pv[nt][r] = s;
              m = fmaxf(m, s);
            }
        } else {
#pragma unroll
          for (int nt = 0; nt < 4; ++nt)
#pragma unroll
            for (int r = 0; r < 4; ++r) {
              float s = sc[nt][r];
              pv[nt][r] = s;
              m = fmaxf(m, s);
            }
        }
        m = fmaxf(m, __shfl_xor(m, 16));
        m = fmaxf(m, __shfl_xor(m, 32));

        if (!__all(m - m_run <= 8.0f)) {
          const float m_new = fmaxf(m_run, m);
          const float corr = fexp2(m_run - m_new);
          l_run *= corr;
#pragma unroll
          for (int mt = 0; mt < 4; ++mt)
#pragma unroll
            for (int r = 0; r < 4; ++r) acc[mt][r] *= corr;
          m_run = m_new;
        }

        float rsum = 0.f;
#pragma unroll
        for (int nt = 0; nt < 4; ++nt)
#pragma unroll
          for (int r = 0; r < 4; ++r) {
            float e = fexp2(pv[nt][r] - m_run);
            pv[nt][r] = e;
            rsum += e;
          }
        rsum += __shfl_xor(rsum, 16);
        rsum += __shfl_xor(rsum, 32);
        l_run += rsum;

#pragma unroll
        for (int nt = 0; nt < 4; ++nt) {
          short4v pw;
#pragma unroll
          for (int r = 0; r < 4; ++r) pw[r] = f2bf(pv[nt][r]);
          int off = (l15 * 128 + nt * 32 + lq * 8) ^ ((l15 & 7) << 4);
          *(short4v*)((char*)sPw + off) = pw;
        }

        __builtin_amdgcn_s_setprio(1);
#pragma unroll
        for (int ks = 0; ks < 2; ++ks) {
          int poff = (l15 * 128 + ks * 64 + lq * 16) ^ ((l15 & 7) << 4);
          short8 pf = *(const short8*)((const char*)sPw + poff);
#pragma unroll
          for (int mt = 0; mt < 4; ++mt) {
            int row = mt * 16 + l15;
            int voff = (row * 128 + ks * 64 + lq * 16) ^ ((row & 7) << 4);
            short8 vf = *(const short8*)(bufV + voff);
            acc[mt] = __builtin_amdgcn_mfma_f32_16x16x32_bf16(vf, pf, acc[mt],
                                                              0, 0, 0);
          }
        }
        __builtin_amdgcn_s_setprio(0);
      }

      if (hn) {
        *(short8*)((char*)sK[p ^ 1] + soff) = kreg;
        *(short8*)((char*)sVT[p ^ 1] + soff) = vreg;
      }
      p ^= 1;
    }

    const float rl = 1.0f / l_run;
    short* orow = Oa + ((size_t)(b * 2048 + qg)) * 1024 + h * 64;
#pragma unroll
    for (int mt = 0; mt < 4; ++mt) {
      short4v o;
#pragma unroll
      for (int r = 0; r < 4; ++r) o[r] = f2bf(acc[mt][r] * rl);
      *(short4v*)(orow + mt * 16 + lq * 4) = o;
    }
  }
}

// ---------------------------------------------------------------------------
extern "C" void kernel_launch(void* const* d_in, const int* in_sizes, int n_in,
                              void* d_out, int out_size, void* d_ws,
                              size_t ws_size, hipStream_t stream) {
  const float* q = (const float*)d_in[0];
  const float* k = (const float*)d_in[1];
  const float* v = (const float*)d_in[2];
  const float* Wq = (const float*)d_in[3];
  const float* Wk = (const float*)d_in[4];
  const float* Wv = (const float*)d_in[5];
  const float* Wo = (const float*)d_in[6];

  char* ws = (char*)d_ws;
  short* wq_b = (short*)(ws + (0ull << 20));   // 4 x 2MB bf16 weights
  short* wk_b = (short*)(ws + (2ull << 20));
  short* wv_b = (short*)(ws + (4ull << 20));
  short* wo_b = (short*)(ws + (6ull << 20));
  short* xq  = (short*)(ws + (8ull << 20));    // 16 MB, [B,H,S,Dh] bf16
  short* xk  = (short*)(ws + (24ull << 20));
  short* xvT = (short*)(ws + (40ull << 20));   // 16 MB, [B,H,Dh,S] bf16
  short* oa  = (short*)(ws + (56ull << 20));   // 16 MB, [B,S,D] bf16
  // total 72 MB (ws_size observed >= 122 MB on this harness)

  convert_w4<<<dim3(512, 1, 4), 256, 0, stream>>>(Wq, Wk, Wv, Wo, wq_b);
  proj_gemm3<<<dim3(512, 1, 3), 256, 0, stream>>>(q, k, v, wq_b, wk_b, wv_b,
                                                  xq, xk, xvT);
  attn_k<<<dim3(512), 512, 0, stream>>>(xq, xk, xvT, oa);
  final_gemm<<<dim3(512), 256, 0, stream>>>(oa, wo_b, (float*)d_out);
}

// Round 13
// 180.284 us; speedup vs baseline: 1.0450x; 1.0450x over previous
//
#include <hip/hip_runtime.h>
#include <hip/hip_bf16.h>

#define DI __device__ __forceinline__

typedef __attribute__((ext_vector_type(8))) short short8;
typedef __attribute__((ext_vector_type(4))) short short4v;
typedef __attribute__((ext_vector_type(4))) float f32x4;

// Q pre-scale: 1/sqrt(64) * log2(e)  (exp2-domain softmax)
#define QSCALE 0.180336885f

// RNE float -> bf16 via native fptrunc (compiler packs v_cvt_pk_bf16_f32)
DI short f2bf(float f) {
  __hip_bfloat16 h = __float2bfloat16(f);
  return __builtin_bit_cast(short, h);
}

DI float fexp2(float x) {
#if __has_builtin(__builtin_amdgcn_exp2f)
  return __builtin_amdgcn_exp2f(x);
#else
  return exp2f(x);
#endif
}

// async global->LDS, 16B per lane. LDS dest = wave-uniform base + lane*16.
DI void gl16(const short* g, short* l) {
  __builtin_amdgcn_global_load_lds(
      (const __attribute__((address_space(1))) void*)g,
      (__attribute__((address_space(3))) void*)l, 16, 0, 0);
}

// ---------------------------------------------------------------------------
// All fp32->bf16 conversions in ONE launch.
// z 0..2: q/k/v [8192x1024] (4096 blocks x 8 elems). z 3..6: W* (512 blocks).
// ---------------------------------------------------------------------------
__global__ __launch_bounds__(256) void convert_all(
    const float* __restrict__ q, const float* __restrict__ k,
    const float* __restrict__ v, const float* __restrict__ wq,
    const float* __restrict__ wk, const float* __restrict__ wv,
    const float* __restrict__ wo, short* __restrict__ qb,
    short* __restrict__ kb, short* __restrict__ vb, short* __restrict__ wb) {
  int z = blockIdx.z;
  const float* src;
  short* dst;
  if (z < 3) {
    src = (z == 0) ? q : (z == 1) ? k : v;
    dst = (z == 0) ? qb : (z == 1) ? kb : vb;
  } else {
    if (blockIdx.x >= 512) return;
    src = (z == 3) ? wq : (z == 4) ? wk : (z == 5) ? wv : wo;
    dst = wb + (size_t)(z - 3) * 1024 * 1024;
  }
  size_t i = ((size_t)blockIdx.x * 256 + threadIdx.x) * 8;
  float4 f0 = *(const float4*)(src + i);
  float4 f1 = *(const float4*)(src + i + 4);
  short8 o;
  o[0] = f2bf(f0.x); o[1] = f2bf(f0.y); o[2] = f2bf(f0.z); o[3] = f2bf(f0.w);
  o[4] = f2bf(f1.x); o[5] = f2bf(f1.y); o[6] = f2bf(f1.z); o[7] = f2bf(f1.w);
  *(short8*)(dst + i) = o;
}

// single src->dst convert (fallback path)
__global__ __launch_bounds__(256) void convert_one(
    const float* __restrict__ src, short* __restrict__ dst) {
  size_t i = ((size_t)blockIdx.x * 256 + threadIdx.x) * 8;
  float4 f0 = *(const float4*)(src + i);
  float4 f1 = *(const float4*)(src + i + 4);
  short8 o;
  o[0] = f2bf(f0.x); o[1] = f2bf(f0.y); o[2] = f2bf(f0.z); o[3] = f2bf(f0.w);
  o[4] = f2bf(f1.x); o[5] = f2bf(f1.y); o[6] = f2bf(f1.z); o[7] = f2bf(f1.w);
  *(short8*)(dst + i) = o;
}

// ---------------------------------------------------------------------------
// bf16 GEMM core (R9 single-buffered 2-barrier structure, gl16 staging).
// NEW: MFMA operand order chosen per OMODE so the per-thread r-index walks
// the output's CONTIGUOUS dim -> vector stores (was 64x scalar stores):
//   OUT_HEAD (xq/xk [B,H,S,Dh]): swapped mfma(b,a) -> r = feature -> short4v
//   OUT_F32  (out  [BS, D])    : swapped mfma(b,a) -> r = col     -> float4
//   OUT_HEADT(xvT [B,H,Dh,S])  : normal  mfma(a,b) -> r = token   -> short4v
// ---------------------------------------------------------------------------
enum { OUT_F32 = 0, OUT_HEAD = 1, OUT_HEADT = 2 };

template <int OMODE>
DI void gemm_core(short* sA, short* sB, const short* __restrict__ A,
                  const short* __restrict__ B, void* __restrict__ Cp,
                  float scale, int bm, int bn) {
  const int tid = threadIdx.x;
  const int lane = tid & 63;
  const int wid = tid >> 6;
  const int wm = wid >> 1, wn = wid & 1;
  const int l15 = lane & 15, lq = lane >> 4;
  const int lrr = lane >> 3;  // row within 8-row group
  const int lch = lane & 7;   // 16B chunk within 128B row

  f32x4 acc[4][4] = {};

  for (int k0 = 0; k0 < 1024; k0 += 64) {
#pragma unroll
    for (int i = 0; i < 4; ++i) {
      int r0 = wid * 32 + i * 8;
      int rr = r0 + lrr;
      int sc = (lch ^ (rr & 7)) << 3;  // inverse-swizzled source chunk (shorts)
      gl16(A + (size_t)(bm + rr) * 1024 + k0 + sc, sA + r0 * 64);
      gl16(B + (size_t)(bn + rr) * 1024 + k0 + sc, sB + r0 * 64);
    }
    __syncthreads();  // drains vmcnt before barrier

#pragma unroll
    for (int ks = 0; ks < 2; ++ks) {
      short8 a[4], b[4];
#pragma unroll
      for (int mt = 0; mt < 4; ++mt) {
        int row = wm * 64 + mt * 16 + l15;
        int off = (row * 128 + ks * 64 + lq * 16) ^ ((row & 7) << 4);
        a[mt] = *(const short8*)((const char*)sA + off);
      }
#pragma unroll
      for (int nt = 0; nt < 4; ++nt) {
        int row = wn * 64 + nt * 16 + l15;
        int off = (row * 128 + ks * 64 + lq * 16) ^ ((row & 7) << 4);
        b[nt] = *(const short8*)((const char*)sB + off);
      }
#pragma unroll
      for (int mt = 0; mt < 4; ++mt)
#pragma unroll
        for (int nt = 0; nt < 4; ++nt) {
          if (OMODE == OUT_HEADT)
            acc[mt][nt] = __builtin_amdgcn_mfma_f32_16x16x32_bf16(
                a[mt], b[nt], acc[mt][nt], 0, 0, 0);  // normal: r = token
          else
            acc[mt][nt] = __builtin_amdgcn_mfma_f32_16x16x32_bf16(
                b[nt], a[mt], acc[mt][nt], 0, 0, 0);  // swapped: r = col/feat
        }
    }
    __syncthreads();
  }

  // ---- vectorized epilogue ----
#pragma unroll
  for (int mt = 0; mt < 4; ++mt) {
#pragma unroll
    for (int nt = 0; nt < 4; ++nt) {
      if (OMODE == OUT_HEAD) {
        // swapped: token t = m-space + l15 ; feature f = n-space + lq*4+r
        int t = bm + wm * 64 + mt * 16 + l15;
        int f0 = bn + wn * 64 + nt * 16 + lq * 4;
        int bb = t >> 11, s = t & 2047;
        int h = f0 >> 6, dh0 = f0 & 63;
        short4v o;
#pragma unroll
        for (int r = 0; r < 4; ++r) o[r] = f2bf(acc[mt][nt][r] * scale);
        *(short4v*)((short*)Cp + ((size_t)((bb * 16 + h) * 2048 + s)) * 64 +
                    dh0) = o;
      } else if (OMODE == OUT_F32) {
        int t = bm + wm * 64 + mt * 16 + l15;
        int f0 = bn + wn * 64 + nt * 16 + lq * 4;
        float4 o;
        o.x = acc[mt][nt][0] * scale;
        o.y = acc[mt][nt][1] * scale;
        o.z = acc[mt][nt][2] * scale;
        o.w = acc[mt][nt][3] * scale;
        *(float4*)((float*)Cp + (size_t)t * 1024 + f0) = o;
      } else {  // OUT_HEADT, normal: token t = m-space + lq*4+r ; feat = l15
        int t0 = bm + wm * 64 + mt * 16 + lq * 4;
        int f = bn + wn * 64 + nt * 16 + l15;
        int bb = t0 >> 11, s0 = t0 & 2047;
        int h = f >> 6, dh = f & 63;
        short4v o;
#pragma unroll
        for (int r = 0; r < 4; ++r) o[r] = f2bf(acc[mt][nt][r] * scale);
        *(short4v*)((short*)Cp + ((size_t)((bb * 16 + h) * 64 + dh)) * 2048 +
                    s0) = o;
      }
    }
  }
}

// XCD-aware tile mapping: 8 n-tiles of one A row-panel run consecutively on
// ONE XCD (id&7 = xcd under round-robin dispatch) -> A panel read once.
DI void xcd_map(int id, int& bm, int& bn) {
  int xcd = id & 7, slot = id >> 3;
  int panel = xcd + 8 * (slot >> 3);
  int ntile = slot & 7;
  bm = panel * 128;
  bn = ntile * 128;
}

#define GEMM_LDS()                              \
  __shared__ __align__(16) short sA[128 * 64];  \
  __shared__ __align__(16) short sB[128 * 64];

__global__ __launch_bounds__(256) void proj_gemm3(
    const short* __restrict__ qb, const short* __restrict__ kb,
    const short* __restrict__ vb, const short* __restrict__ wq,
    const short* __restrict__ wk, const short* __restrict__ wv,
    short* __restrict__ xq, short* __restrict__ xk, short* __restrict__ xvT) {
  GEMM_LDS();
  int z = blockIdx.z;
  int bm, bn;
  xcd_map(blockIdx.x, bm, bn);
  if (z == 0) {
    gemm_core<OUT_HEAD>(sA, sB, qb, wq, xq, QSCALE, bm, bn);
  } else if (z == 1) {
    gemm_core<OUT_HEAD>(sA, sB, kb, wk, xk, 1.0f, bm, bn);
  } else {
    gemm_core<OUT_HEADT>(sA, sB, vb, wv, xvT, 1.0f, bm, bn);
  }
}

__global__ __launch_bounds__(256) void proj_oneN(
    const short* __restrict__ A, const short* __restrict__ B,
    short* __restrict__ C, float scale) {
  GEMM_LDS();
  int bm, bn;
  xcd_map(blockIdx.x, bm, bn);
  gemm_core<OUT_HEAD>(sA, sB, A, B, C, scale, bm, bn);
}

__global__ __launch_bounds__(256) void proj_oneT(
    const short* __restrict__ A, const short* __restrict__ B,
    short* __restrict__ C, float scale) {
  GEMM_LDS();
  int bm, bn;
  xcd_map(blockIdx.x, bm, bn);
  gemm_core<OUT_HEADT>(sA, sB, A, B, C, scale, bm, bn);
}

__global__ __launch_bounds__(256) void final_gemm(
    const short* __restrict__ oa, const short* __restrict__ wo,
    float* __restrict__ out) {
  GEMM_LDS();
  int bm, bn;
  xcd_map(blockIdx.x, bm, bn);
  gemm_core<OUT_F32>(sA, sB, oa, wo, out, 1.0f, bm, bn);
}

// ---------------------------------------------------------------------------
// Causal flash attention (known-good R8/R9 version, unchanged).
// 512 threads = 8 waves; 128-row q-supertile; pairs (i, 15-i) -> 34 KV
// tiles/block, 512 blocks. Double-buffered K/V^T LDS, ONE barrier per tile.
// LDS = 32KB (K,VT dbuf) + 16KB (P) = 48KB.
// ---------------------------------------------------------------------------
__global__ __launch_bounds__(512, 4) void attn_k(
    const short* __restrict__ Xq, const short* __restrict__ Xk,
    const short* __restrict__ XvT, short* __restrict__ Oa) {
  __shared__ __align__(16) short sK[2][64 * 64];
  __shared__ __align__(16) short sVT[2][64 * 64];
  __shared__ __align__(16) short sP[8][16 * 64];

  const int tid = threadIdx.x;
  const int lane = tid & 63;
  const int wid = tid >> 6;  // 0..7
  const int l15 = lane & 15, lq = lane >> 4;
  const int bid = blockIdx.x;
  const int ipair = bid >> 6;  // 0..7
  const int bh = bid & 63;     // same-bh blocks land on same XCD
  const int b = bh >> 4, h = bh & 15;

  const short* Q = Xq + (size_t)bh * 2048 * 64;
  const short* K = Xk + (size_t)bh * 2048 * 64;
  const short* VT = XvT + (size_t)bh * 64 * 2048;

  const int srow = tid >> 3;       // 0..63
  const int scol = (tid & 7) * 8;  // 0..56
  const int soff = (srow * 128 + scol * 2) ^ ((srow & 7) << 4);

  short8 kreg, vreg;
  kreg = *(const short8*)(K + (size_t)srow * 64 + scol);
  vreg = *(const short8*)(VT + (size_t)srow * 2048 + scol);

  *(short8*)((char*)sK[0] + soff) = kreg;
  *(short8*)((char*)sVT[0] + soff) = vreg;

  short* sPw = sP[wid];
  int p = 0;

  for (int seg = 0; seg < 2; ++seg) {
    const int qt = seg ? ipair : (15 - ipair);  // long supertile first
    const int qfirst = qt * 128 + wid * 16;
    const int qg = qfirst + l15;
    const int qlast = qfirst + 15;
    const int ntile = 2 * qt + 2;

    short8 qf[2];
#pragma unroll
    for (int ks = 0; ks < 2; ++ks)
      qf[ks] = *(const short8*)(Q + (size_t)qg * 64 + ks * 32 + lq * 8);

    float m_run = -1e30f, l_run = 0.f;
    f32x4 acc[4] = {};

    for (int kt = 0; kt < ntile; ++kt) {
      const int kv0 = kt * 64;
      __syncthreads();

      int nkt = kt + 1, nseg = seg;
      if (nkt >= ntile) { nseg = seg + 1; nkt = 0; }
      const bool hn = (nseg < 2);
      if (hn) {
        const int kn = nkt * 64;
        kreg = *(const short8*)(K + (size_t)(kn + srow) * 64 + scol);
        vreg = *(const short8*)(VT + (size_t)srow * 2048 + kn + scol);
      }

      const bool fullmask = (kv0 > qlast);
      if (!fullmask) {
        const bool needmask = (kv0 + 63 > qfirst);
        const char* bufK = (const char*)sK[p];
        const char* bufV = (const char*)sVT[p];

        f32x4 sc[4] = {};
        __builtin_amdgcn_s_setprio(1);
#pragma unroll
        for (int ks = 0; ks < 2; ++ks) {
          short8 kf[4];
#pragma unroll
          for (int nt = 0; nt < 4; ++nt) {
            int row = nt * 16 + l15;
            int off = (row * 128 + ks * 64 + lq * 16) ^ ((row & 7) << 4);
            kf[nt] = *(const short8*)(bufK + off);
          }
#pragma unroll
          for (int nt = 0; nt < 4; ++nt)
            sc[nt] = __builtin_amdgcn_mfma_f32_16x16x32_bf16(kf[nt], qf[ks],
                                                             sc[nt], 0, 0, 0);
        }
        __builtin_amdgcn_s_setprio(0);

        float pv[4][4];
        float m = -1e30f;
        if (needmask) {
#pragma unroll
          for (int nt = 0; nt < 4; ++nt)
#pragma unroll
            for (int r = 0; r < 4; ++r) {
              float s = sc[nt][r];
              if (kv0 + nt * 16 + lq * 4 + r > qg) s = -1e30f;
              pv[nt][r] = s;
              m = fmaxf(m, s);
            }
        } else {
#pragma unroll
          for (int nt = 0; nt < 4; ++nt)
#pragma unroll
            for (int r = 0; r < 4; ++r) {
              float s = sc[nt][r];
              pv[nt][r] = s;
              m = fmaxf(m, s);
            }
        }
        m = fmaxf(m, __shfl_xor(m, 16));
        m = fmaxf(m, __shfl_xor(m, 32));

        if (!__all(m - m_run <= 8.0f)) {
          const float m_new = fmaxf(m_run, m);
          const float corr = fexp2(m_run - m_new);
          l_run *= corr;
#pragma unroll
          for (int mt = 0; mt < 4; ++mt)
#pragma unroll
            for (int r = 0; r < 4; ++r) acc[mt][r] *= corr;
          m_run = m_new;
        }

        float rsum = 0.f;
#pragma unroll
        for (int nt = 0; nt < 4; ++nt)
#pragma unroll
          for (int r = 0; r < 4; ++r) {
            float e = fexp2(pv[nt][r] - m_run);
            pv[nt][r] = e;
            rsum += e;
          }
        rsum += __shfl_xor(rsum, 16);
        rsum += __shfl_xor(rsum, 32);
        l_run += rsum;

#pragma unroll
        for (int nt = 0; nt < 4; ++nt) {
          short4v pw;
#pragma unroll
          for (int r = 0; r < 4; ++r) pw[r] = f2bf(pv[nt][r]);
          int off = (l15 * 128 + nt * 32 + lq * 8) ^ ((l15 & 7) << 4);
          *(short4v*)((char*)sPw + off) = pw;
        }

        __builtin_amdgcn_s_setprio(1);
#pragma unroll
        for (int ks = 0; ks < 2; ++ks) {
          int poff = (l15 * 128 + ks * 64 + lq * 16) ^ ((l15 & 7) << 4);
          short8 pf = *(const short8*)((const char*)sPw + poff);
#pragma unroll
          for (int mt = 0; mt < 4; ++mt) {
            int row = mt * 16 + l15;
            int voff = (row * 128 + ks * 64 + lq * 16) ^ ((row & 7) << 4);
            short8 vf = *(const short8*)(bufV + voff);
            acc[mt] = __builtin_amdgcn_mfma_f32_16x16x32_bf16(vf, pf, acc[mt],
                                                              0, 0, 0);
          }
        }
        __builtin_amdgcn_s_setprio(0);
      }

      if (hn) {
        *(short8*)((char*)sK[p ^ 1] + soff) = kreg;
        *(short8*)((char*)sVT[p ^ 1] + soff) = vreg;
      }
      p ^= 1;
    }

    const float rl = 1.0f / l_run;
    short* orow = Oa + ((size_t)(b * 2048 + qg)) * 1024 + h * 64;
#pragma unroll
    for (int mt = 0; mt < 4; ++mt) {
      short4v o;
#pragma unroll
      for (int r = 0; r < 4; ++r) o[r] = f2bf(acc[mt][r] * rl);
      *(short4v*)(orow + mt * 16 + lq * 4) = o;
    }
  }
}

// ---------------------------------------------------------------------------
extern "C" void kernel_launch(void* const* d_in, const int* in_sizes, int n_in,
                              void* d_out, int out_size, void* d_ws,
                              size_t ws_size, hipStream_t stream) {
  const float* q = (const float*)d_in[0];
  const float* k = (const float*)d_in[1];
  const float* v = (const float*)d_in[2];
  const float* Wq = (const float*)d_in[3];
  const float* Wk = (const float*)d_in[4];
  const float* Wv = (const float*)d_in[5];
  const float* Wo = (const float*)d_in[6];

  char* ws = (char*)d_ws;
  short* wq_b = (short*)(ws + (0ull << 20));
  short* wk_b = (short*)(ws + (2ull << 20));
  short* wv_b = (short*)(ws + (4ull << 20));
  short* wo_b = (short*)(ws + (6ull << 20));
  short* xq  = (short*)(ws + (8ull << 20));    // 16 MB each, [B,H,S,Dh] bf16
  short* xk  = (short*)(ws + (24ull << 20));
  short* xvT = (short*)(ws + (56ull << 20));   // [B,H,Dh,S] bf16

  if (ws_size >= (122ull << 20)) {
    short* qb = (short*)(ws + (72ull << 20));  // 16 MB each, [B*S, D] bf16
    short* kb = (short*)(ws + (88ull << 20));
    short* vb = (short*)(ws + (104ull << 20));
    short* oa = qb;  // qb dead after proj_gemm3

    convert_all<<<dim3(4096, 1, 7), 256, 0, stream>>>(q, k, v, Wq, Wk, Wv, Wo,
                                                      qb, kb, vb, wq_b);
    proj_gemm3<<<dim3(512, 1, 3), 256, 0, stream>>>(qb, kb, vb, wq_b, wk_b,
                                                    wv_b, xq, xk, xvT);
    attn_k<<<dim3(512), 512, 0, stream>>>(xq, xk, xvT, oa);
    final_gemm<<<dim3(512), 256, 0, stream>>>(oa, wo_b, (float*)d_out);
  } else {
    // ping-pong fallback: one 16 MB staging buffer, sequential per-z
    short* X = (short*)(ws + (8ull << 20));
    short* xq2 = (short*)(ws + (24ull << 20));
    short* xk2 = (short*)(ws + (40ull << 20));
    short* xvT2 = (short*)(ws + (56ull << 20));
    short* oa2 = (short*)(ws + (72ull << 20));

    convert_one<<<dim3(512), 256, 0, stream>>>(Wq, wq_b);
    convert_one<<<dim3(512), 256, 0, stream>>>(Wk, wk_b);
    convert_one<<<dim3(512), 256, 0, stream>>>(Wv, wv_b);
    convert_one<<<dim3(512), 256, 0, stream>>>(Wo, wo_b);
    convert_one<<<dim3(4096), 256, 0, stream>>>(q, X);
    proj_oneN<<<dim3(512), 256, 0, stream>>>(X, wq_b, xq2, QSCALE);
    convert_one<<<dim3(4096), 256, 0, stream>>>(k, X);
    proj_oneN<<<dim3(512), 256, 0, stream>>>(X, wk_b, xk2, 1.0f);
    convert_one<<<dim3(4096), 256, 0, stream>>>(v, X);
    proj_oneT<<<dim3(512), 256, 0, stream>>>(X, wv_b, xvT2, 1.0f);
    attn_k<<<dim3(512), 512, 0, stream>>>(xq2, xk2, xvT2, oa2);
    final_gemm<<<dim3(512), 256, 0, stream>>>(oa2, wo_b, (float*)d_out);
  }
}

// Round 14
// 173.890 us; speedup vs baseline: 1.0834x; 1.0368x over previous
//
#include <hip/hip_runtime.h>
#include <hip/hip_bf16.h>

#define DI __device__ __forceinline__

typedef __attribute__((ext_vector_type(8))) short short8;
typedef __attribute__((ext_vector_type(4))) short short4v;
typedef __attribute__((ext_vector_type(4))) float f32x4;

// Q pre-scale: 1/sqrt(64) * log2(e)  (exp2-domain softmax)
#define QSCALE 0.180336885f

// RNE float -> bf16 via native fptrunc (compiler packs v_cvt_pk_bf16_f32)
DI short f2bf(float f) {
  __hip_bfloat16 h = __float2bfloat16(f);
  return __builtin_bit_cast(short, h);
}

DI float fexp2(float x) {
#if __has_builtin(__builtin_amdgcn_exp2f)
  return __builtin_amdgcn_exp2f(x);
#else
  return exp2f(x);
#endif
}

// async global->LDS, 16B per lane. LDS dest = wave-uniform base + lane*16.
DI void gl16(const short* g, short* l) {
  __builtin_amdgcn_global_load_lds(
      (const __attribute__((address_space(1))) void*)g,
      (__attribute__((address_space(3))) void*)l, 16, 0, 0);
}

// ---------------------------------------------------------------------------
// All fp32->bf16 conversions in ONE launch.
// z 0..2: q/k/v [8192x1024] (4096 blocks x 8 elems). z 3..6: W* (512 blocks).
// ---------------------------------------------------------------------------
__global__ __launch_bounds__(256) void convert_all(
    const float* __restrict__ q, const float* __restrict__ k,
    const float* __restrict__ v, const float* __restrict__ wq,
    const float* __restrict__ wk, const float* __restrict__ wv,
    const float* __restrict__ wo, short* __restrict__ qb,
    short* __restrict__ kb, short* __restrict__ vb, short* __restrict__ wb) {
  int z = blockIdx.z;
  const float* src;
  short* dst;
  if (z < 3) {
    src = (z == 0) ? q : (z == 1) ? k : v;
    dst = (z == 0) ? qb : (z == 1) ? kb : vb;
  } else {
    if (blockIdx.x >= 512) return;
    src = (z == 3) ? wq : (z == 4) ? wk : (z == 5) ? wv : wo;
    dst = wb + (size_t)(z - 3) * 1024 * 1024;
  }
  size_t i = ((size_t)blockIdx.x * 256 + threadIdx.x) * 8;
  float4 f0 = *(const float4*)(src + i);
  float4 f1 = *(const float4*)(src + i + 4);
  short8 o;
  o[0] = f2bf(f0.x); o[1] = f2bf(f0.y); o[2] = f2bf(f0.z); o[3] = f2bf(f0.w);
  o[4] = f2bf(f1.x); o[5] = f2bf(f1.y); o[6] = f2bf(f1.z); o[7] = f2bf(f1.w);
  *(short8*)(dst + i) = o;
}

// single src->dst convert (fallback path)
__global__ __launch_bounds__(256) void convert_one(
    const float* __restrict__ src, short* __restrict__ dst) {
  size_t i = ((size_t)blockIdx.x * 256 + threadIdx.x) * 8;
  float4 f0 = *(const float4*)(src + i);
  float4 f1 = *(const float4*)(src + i + 4);
  short8 o;
  o[0] = f2bf(f0.x); o[1] = f2bf(f0.y); o[2] = f2bf(f0.z); o[3] = f2bf(f0.w);
  o[4] = f2bf(f1.x); o[5] = f2bf(f1.y); o[6] = f2bf(f1.z); o[7] = f2bf(f1.w);
  *(short8*)(dst + i) = o;
}

// ---------------------------------------------------------------------------
// bf16 GEMM core: double-buffered gl16 staging with COUNTED vmcnt (T4).
// Per K-step: issue 8 gl16 for tile t+1 into buf^1, s_waitcnt vmcnt(8)
// (waits only the 8 OLDER tile-t loads), raw s_barrier, compute buf,
// raw s_barrier (no drain: all ds_reads are consumed by MFMAs before it;
// tile t+2 writes are gl16s issued after it). Prefetch loads stay in
// flight across barriers -- removes the vmcnt(0) drain stall of
// __syncthreads (the documented ~20% m97-structure stall).
// Epilogue/operand order = R9 (71.6us measured; R13's swap regressed).
// ---------------------------------------------------------------------------
enum { OUT_F32 = 0, OUT_HEAD = 1, OUT_HEADT = 2 };

DI void stage_tile(const short* __restrict__ A, const short* __restrict__ B,
                   short* dA, short* dB, int bm, int bn, int k0, int wid,
                   int lrr, int lch) {
#pragma unroll
  for (int i = 0; i < 4; ++i) {
    int r0 = wid * 32 + i * 8;
    int rr = r0 + lrr;
    int sc = (lch ^ (rr & 7)) << 3;  // inverse-swizzled source chunk (shorts)
    gl16(A + (size_t)(bm + rr) * 1024 + k0 + sc, dA + r0 * 64);
    gl16(B + (size_t)(bn + rr) * 1024 + k0 + sc, dB + r0 * 64);
  }
}

template <int OMODE>
DI void gemm_core(short* sA, short* sB, const short* __restrict__ A,
                  const short* __restrict__ B, void* __restrict__ Cp,
                  float scale, int bm, int bn) {
  const int tid = threadIdx.x;
  const int lane = tid & 63;
  const int wid = tid >> 6;
  const int wm = wid >> 1, wn = wid & 1;
  const int l15 = lane & 15, lq = lane >> 4;
  const int lrr = lane >> 3;  // row within 8-row group
  const int lch = lane & 7;   // 16B chunk within 128B row

  f32x4 acc[4][4] = {};

  // prologue: tile 0 -> buffer 0 (8 loads in flight)
  stage_tile(A, B, sA, sB, bm, bn, 0, wid, lrr, lch);

  int cur = 0;
  for (int t = 0; t < 16; ++t) {
    if (t < 15) {
      // issue tile t+1 (8 more loads) then wait ONLY for tile t's 8
      stage_tile(A, B, sA + (cur ^ 1) * 8192, sB + (cur ^ 1) * 8192, bm, bn,
                 (t + 1) * 64, wid, lrr, lch);
      asm volatile("s_waitcnt vmcnt(8)" ::: "memory");
    } else {
      asm volatile("s_waitcnt vmcnt(0)" ::: "memory");
    }
    __builtin_amdgcn_s_barrier();  // all waves' tile-t loads landed

    const char* bA = (const char*)(sA + cur * 8192);
    const char* bB = (const char*)(sB + cur * 8192);
#pragma unroll
    for (int ks = 0; ks < 2; ++ks) {
      short8 a[4], b[4];
#pragma unroll
      for (int mt = 0; mt < 4; ++mt) {
        int row = wm * 64 + mt * 16 + l15;
        int off = (row * 128 + ks * 64 + lq * 16) ^ ((row & 7) << 4);
        a[mt] = *(const short8*)(bA + off);
      }
#pragma unroll
      for (int nt = 0; nt < 4; ++nt) {
        int row = wn * 64 + nt * 16 + l15;
        int off = (row * 128 + ks * 64 + lq * 16) ^ ((row & 7) << 4);
        b[nt] = *(const short8*)(bB + off);
      }
#pragma unroll
      for (int mt = 0; mt < 4; ++mt)
#pragma unroll
        for (int nt = 0; nt < 4; ++nt) {
          if (OMODE == OUT_HEADT)
            acc[mt][nt] = __builtin_amdgcn_mfma_f32_16x16x32_bf16(
                b[nt], a[mt], acc[mt][nt], 0, 0, 0);
          else
            acc[mt][nt] = __builtin_amdgcn_mfma_f32_16x16x32_bf16(
                a[mt], b[nt], acc[mt][nt], 0, 0, 0);
        }
    }
    __builtin_amdgcn_s_barrier();  // all waves done reading buf[cur]
    cur ^= 1;
  }

  // ---- epilogue (R9 layout) ----
#pragma unroll
  for (int mt = 0; mt < 4; ++mt) {
#pragma unroll
    for (int nt = 0; nt < 4; ++nt) {
#pragma unroll
      for (int r = 0; r < 4; ++r) {
        float val = acc[mt][nt][r] * scale;
        if (OMODE == OUT_HEADT) {
          int f = bn + wn * 64 + nt * 16 + lq * 4 + r;
          int t = bm + wm * 64 + mt * 16 + l15;
          int bb = t >> 11, s = t & 2047;
          int h = f >> 6, dh = f & 63;
          ((short*)Cp)[((size_t)((bb * 16 + h) * 64 + dh)) * 2048 + s] = f2bf(val);
        } else {
          int rowg = bm + wm * 64 + mt * 16 + lq * 4 + r;
          int colg = bn + wn * 64 + nt * 16 + l15;
          if (OMODE == OUT_HEAD) {
            int bb = rowg >> 11, s = rowg & 2047;
            int h = colg >> 6, dh = colg & 63;
            ((short*)Cp)[((size_t)(bb * 16 + h) * 2048 + s) * 64 + dh] = f2bf(val);
          } else {
            ((float*)Cp)[(size_t)rowg * 1024 + colg] = val;
          }
        }
      }
    }
  }
}

// XCD-aware tile mapping: 8 n-tiles of one A row-panel run consecutively on
// ONE XCD (id&7 = xcd under round-robin dispatch) -> A panel read once.
DI void xcd_map(int id, int& bm, int& bn) {
  int xcd = id & 7, slot = id >> 3;
  int panel = xcd + 8 * (slot >> 3);
  int ntile = slot & 7;
  bm = panel * 128;
  bn = ntile * 128;
}

#define GEMM_LDS()                                  \
  __shared__ __align__(16) short sA[2 * 128 * 64];  \
  __shared__ __align__(16) short sB[2 * 128 * 64];

__global__ __launch_bounds__(256) void proj_gemm3(
    const short* __restrict__ qb, const short* __restrict__ kb,
    const short* __restrict__ vb, const short* __restrict__ wq,
    const short* __restrict__ wk, const short* __restrict__ wv,
    short* __restrict__ xq, short* __restrict__ xk, short* __restrict__ xvT) {
  GEMM_LDS();
  int z = blockIdx.z;
  int bm, bn;
  xcd_map(blockIdx.x, bm, bn);
  if (z == 0) {
    gemm_core<OUT_HEAD>(sA, sB, qb, wq, xq, QSCALE, bm, bn);
  } else if (z == 1) {
    gemm_core<OUT_HEAD>(sA, sB, kb, wk, xk, 1.0f, bm, bn);
  } else {
    gemm_core<OUT_HEADT>(sA, sB, vb, wv, xvT, 1.0f, bm, bn);
  }
}

__global__ __launch_bounds__(256) void proj_oneN(
    const short* __restrict__ A, const short* __restrict__ B,
    short* __restrict__ C, float scale) {
  GEMM_LDS();
  int bm, bn;
  xcd_map(blockIdx.x, bm, bn);
  gemm_core<OUT_HEAD>(sA, sB, A, B, C, scale, bm, bn);
}

__global__ __launch_bounds__(256) void proj_oneT(
    const short* __restrict__ A, const short* __restrict__ B,
    short* __restrict__ C, float scale) {
  GEMM_LDS();
  int bm, bn;
  xcd_map(blockIdx.x, bm, bn);
  gemm_core<OUT_HEADT>(sA, sB, A, B, C, scale, bm, bn);
}

__global__ __launch_bounds__(256) void final_gemm(
    const short* __restrict__ oa, const short* __restrict__ wo,
    float* __restrict__ out) {
  GEMM_LDS();
  int bm, bn;
  xcd_map(blockIdx.x, bm, bn);
  gemm_core<OUT_F32>(sA, sB, oa, wo, out, 1.0f, bm, bn);
}

// ---------------------------------------------------------------------------
// Causal flash attention (known-good R8/R9 version, unchanged).
// 512 threads = 8 waves; 128-row q-supertile; pairs (i, 15-i) -> 34 KV
// tiles/block, 512 blocks. Double-buffered K/V^T LDS, ONE barrier per tile.
// LDS = 32KB (K,VT dbuf) + 16KB (P) = 48KB.
// ---------------------------------------------------------------------------
__global__ __launch_bounds__(512, 4) void attn_k(
    const short* __restrict__ Xq, const short* __restrict__ Xk,
    const short* __restrict__ XvT, short* __restrict__ Oa) {
  __shared__ __align__(16) short sK[2][64 * 64];
  __shared__ __align__(16) short sVT[2][64 * 64];
  __shared__ __align__(16) short sP[8][16 * 64];

  const int tid = threadIdx.x;
  const int lane = tid & 63;
  const int wid = tid >> 6;  // 0..7
  const int l15 = lane & 15, lq = lane >> 4;
  const int bid = blockIdx.x;
  const int ipair = bid >> 6;  // 0..7
  const int bh = bid & 63;     // same-bh blocks land on same XCD
  const int b = bh >> 4, h = bh & 15;

  const short* Q = Xq + (size_t)bh * 2048 * 64;
  const short* K = Xk + (size_t)bh * 2048 * 64;
  const short* VT = XvT + (size_t)bh * 64 * 2048;

  const int srow = tid >> 3;       // 0..63
  const int scol = (tid & 7) * 8;  // 0..56
  const int soff = (srow * 128 + scol * 2) ^ ((srow & 7) << 4);

  short8 kreg, vreg;
  kreg = *(const short8*)(K + (size_t)srow * 64 + scol);
  vreg = *(const short8*)(VT + (size_t)srow * 2048 + scol);

  *(short8*)((char*)sK[0] + soff) = kreg;
  *(short8*)((char*)sVT[0] + soff) = vreg;

  short* sPw = sP[wid];
  int p = 0;

  for (int seg = 0; seg < 2; ++seg) {
    const int qt = seg ? ipair : (15 - ipair);  // long supertile first
    const int qfirst = qt * 128 + wid * 16;
    const int qg = qfirst + l15;
    const int qlast = qfirst + 15;
    const int ntile = 2 * qt + 2;

    short8 qf[2];
#pragma unroll
    for (int ks = 0; ks < 2; ++ks)
      qf[ks] = *(const short8*)(Q + (size_t)qg * 64 + ks * 32 + lq * 8);

    float m_run = -1e30f, l_run = 0.f;
    f32x4 acc[4] = {};

    for (int kt = 0; kt < ntile; ++kt) {
      const int kv0 = kt * 64;
      __syncthreads();

      int nkt = kt + 1, nseg = seg;
      if (nkt >= ntile) { nseg = seg + 1; nkt = 0; }
      const bool hn = (nseg < 2);
      if (hn) {
        const int kn = nkt * 64;
        kreg = *(const short8*)(K + (size_t)(kn + srow) * 64 + scol);
        vreg = *(const short8*)(VT + (size_t)srow * 2048 + kn + scol);
      }

      const bool fullmask = (kv0 > qlast);
      if (!fullmask) {
        const bool needmask = (kv0 + 63 > qfirst);
        const char* bufK = (const char*)sK[p];
        const char* bufV = (const char*)sVT[p];

        f32x4 sc[4] = {};
        __builtin_amdgcn_s_setprio(1);
#pragma unroll
        for (int ks = 0; ks < 2; ++ks) {
          short8 kf[4];
#pragma unroll
          for (int nt = 0; nt < 4; ++nt) {
            int row = nt * 16 + l15;
            int off = (row * 128 + ks * 64 + lq * 16) ^ ((row & 7) << 4);
            kf[nt] = *(const short8*)(bufK + off);
          }
#pragma unroll
          for (int nt = 0; nt < 4; ++nt)
            sc[nt] = __builtin_amdgcn_mfma_f32_16x16x32_bf16(kf[nt], qf[ks],
                                                             sc[nt], 0, 0, 0);
        }
        __builtin_amdgcn_s_setprio(0);

        float pv[4][4];
        float m = -1e30f;
        if (needmask) {
#pragma unroll
          for (int nt = 0; nt < 4; ++nt)
#pragma unroll
            for (int r = 0; r < 4; ++r) {
              float s = sc[nt][r];
              if (kv0 + nt * 16 + lq * 4 + r > qg) s = -1e30f;
              pv[nt][r] = s;
              m = fmaxf(m, s);
            }
        } else {
#pragma unroll
          for (int nt = 0; nt < 4; ++nt)
#pragma unroll
            for (int r = 0; r < 4; ++r) {
              float s = sc[nt][r];
              pv[nt][r] = s;
              m = fmaxf(m, s);
            }
        }
        m = fmaxf(m, __shfl_xor(m, 16));
        m = fmaxf(m, __shfl_xor(m, 32));

        if (!__all(m - m_run <= 8.0f)) {
          const float m_new = fmaxf(m_run, m);
          const float corr = fexp2(m_run - m_new);
          l_run *= corr;
#pragma unroll
          for (int mt = 0; mt < 4; ++mt)
#pragma unroll
            for (int r = 0; r < 4; ++r) acc[mt][r] *= corr;
          m_run = m_new;
        }

        float rsum = 0.f;
#pragma unroll
        for (int nt = 0; nt < 4; ++nt)
#pragma unroll
          for (int r = 0; r < 4; ++r) {
            float e = fexp2(pv[nt][r] - m_run);
            pv[nt][r] = e;
            rsum += e;
          }
        rsum += __shfl_xor(rsum, 16);
        rsum += __shfl_xor(rsum, 32);
        l_run += rsum;

#pragma unroll
        for (int nt = 0; nt < 4; ++nt) {
          short4v pw;
#pragma unroll
          for (int r = 0; r < 4; ++r) pw[r] = f2bf(pv[nt][r]);
          int off = (l15 * 128 + nt * 32 + lq * 8) ^ ((l15 & 7) << 4);
          *(short4v*)((char*)sPw + off) = pw;
        }

        __builtin_amdgcn_s_setprio(1);
#pragma unroll
        for (int ks = 0; ks < 2; ++ks) {
          int poff = (l15 * 128 + ks * 64 + lq * 16) ^ ((l15 & 7) << 4);
          short8 pf = *(const short8*)((const char*)sPw + poff);
#pragma unroll
          for (int mt = 0; mt < 4; ++mt) {
            int row = mt * 16 + l15;
            int voff = (row * 128 + ks * 64 + lq * 16) ^ ((row & 7) << 4);
            short8 vf = *(const short8*)(bufV + voff);
            acc[mt] = __builtin_amdgcn_mfma_f32_16x16x32_bf16(vf, pf, acc[mt],
                                                              0, 0, 0);
          }
        }
        __builtin_amdgcn_s_setprio(0);
      }

      if (hn) {
        *(short8*)((char*)sK[p ^ 1] + soff) = kreg;
        *(short8*)((char*)sVT[p ^ 1] + soff) = vreg;
      }
      p ^= 1;
    }

    const float rl = 1.0f / l_run;
    short* orow = Oa + ((size_t)(b * 2048 + qg)) * 1024 + h * 64;
#pragma unroll
    for (int mt = 0; mt < 4; ++mt) {
      short4v o;
#pragma unroll
      for (int r = 0; r < 4; ++r) o[r] = f2bf(acc[mt][r] * rl);
      *(short4v*)(orow + mt * 16 + lq * 4) = o;
    }
  }
}

// ---------------------------------------------------------------------------
extern "C" void kernel_launch(void* const* d_in, const int* in_sizes, int n_in,
                              void* d_out, int out_size, void* d_ws,
                              size_t ws_size, hipStream_t stream) {
  const float* q = (const float*)d_in[0];
  const float* k = (const float*)d_in[1];
  const float* v = (const float*)d_in[2];
  const float* Wq = (const float*)d_in[3];
  const float* Wk = (const float*)d_in[4];
  const float* Wv = (const float*)d_in[5];
  const float* Wo = (const float*)d_in[6];

  char* ws = (char*)d_ws;
  short* wq_b = (short*)(ws + (0ull << 20));
  short* wk_b = (short*)(ws + (2ull << 20));
  short* wv_b = (short*)(ws + (4ull << 20));
  short* wo_b = (short*)(ws + (6ull << 20));
  short* xq  = (short*)(ws + (8ull << 20));    // 16 MB each, [B,H,S,Dh] bf16
  short* xk  = (short*)(ws + (24ull << 20));
  short* xvT = (short*)(ws + (56ull << 20));   // [B,H,Dh,S] bf16

  if (ws_size >= (122ull << 20)) {
    short* qb = (short*)(ws + (72ull << 20));  // 16 MB each, [B*S, D] bf16
    short* kb = (short*)(ws + (88ull << 20));
    short* vb = (short*)(ws + (104ull << 20));
    short* oa = qb;  // qb dead after proj_gemm3

    convert_all<<<dim3(4096, 1, 7), 256, 0, stream>>>(q, k, v, Wq, Wk, Wv, Wo,
                                                      qb, kb, vb, wq_b);
    proj_gemm3<<<dim3(512, 1, 3), 256, 0, stream>>>(qb, kb, vb, wq_b, wk_b,
                                                    wv_b, xq, xk, xvT);
    attn_k<<<dim3(512), 512, 0, stream>>>(xq, xk, xvT, oa);
    final_gemm<<<dim3(512), 256, 0, stream>>>(oa, wo_b, (float*)d_out);
  } else {
    // ping-pong fallback: one 16 MB staging buffer, sequential per-z
    short* X = (short*)(ws + (8ull << 20));
    short* xq2 = (short*)(ws + (24ull << 20));
    short* xk2 = (short*)(ws + (40ull << 20));
    short* xvT2 = (short*)(ws + (56ull << 20));
    short* oa2 = (short*)(ws + (72ull << 20));

    convert_one<<<dim3(512), 256, 0, stream>>>(Wq, wq_b);
    convert_one<<<dim3(512), 256, 0, stream>>>(Wk, wk_b);
    convert_one<<<dim3(512), 256, 0, stream>>>(Wv, wv_b);
    convert_one<<<dim3(512), 256, 0, stream>>>(Wo, wo_b);
    convert_one<<<dim3(4096), 256, 0, stream>>>(q, X);
    proj_oneN<<<dim3(512), 256, 0, stream>>>(X, wq_b, xq2, QSCALE);
    convert_one<<<dim3(4096), 256, 0, stream>>>(k, X);
    proj_oneN<<<dim3(512), 256, 0, stream>>>(X, wk_b, xk2, 1.0f);
    convert_one<<<dim3(4096), 256, 0, stream>>>(v, X);
    proj_oneT<<<dim3(512), 256, 0, stream>>>(X, wv_b, xvT2, 1.0f);
    attn_k<<<dim3(512), 512, 0, stream>>>(xq2, xk2, xvT2, oa2);
    final_gemm<<<dim3(512), 256, 0, stream>>>(oa2, wo_b, (float*)d_out);
  }
}